// Round 3
// baseline (357.902 us; speedup 1.0000x reference)
//
#include <hip/hip_runtime.h>

#define Hh 160
#define Ww 160
#define Cc 64
#define HWc 25600
#define Bb 4

typedef __attribute__((ext_vector_type(8))) short short8;
typedef __attribute__((ext_vector_type(4))) float f32x4;

__device__ __forceinline__ unsigned short f2bf(float f) {
  unsigned int u = __float_as_uint(f);
  unsigned int r = u + 0x7FFFu + ((u >> 16) & 1u);
  return (unsigned short)(r >> 16);
}
__device__ __forceinline__ float bflo(unsigned int u) {
  return __uint_as_float(u << 16);
}
__device__ __forceinline__ float bfhi(unsigned int u) {
  return __uint_as_float(u & 0xffff0000u);
}

// ---------------------------------------------------------------------------
// Kernel T: NCHW f32 -> NHWC bf16 transpose. Block = 64 pixels x 64 channels.
// ---------------------------------------------------------------------------
__global__ __launch_bounds__(256) void k_transpose(const float* __restrict__ x,
                                                   unsigned short* __restrict__ xT) {
  __shared__ unsigned short s[64][65];
  int wg = blockIdx.x;           // 1600 = 4b * 400
  int b = wg / 400;
  int pix0 = (wg % 400) * 64;
  int l = threadIdx.x & 63, wv = threadIdx.x >> 6;
  const float* xb = x + (size_t)b * Cc * HWc + pix0;
#pragma unroll
  for (int i = 0; i < 16; i++) {
    int c = i * 4 + wv;
    s[c][l] = f2bf(xb[(size_t)c * HWc + l]);
  }
  __syncthreads();
  int p = threadIdx.x >> 2, ck = threadIdx.x & 3;  // 64 px x 4 chunks of 16 ch
  unsigned int w[8];
#pragma unroll
  for (int j = 0; j < 8; j++) {
    unsigned int a = s[ck * 16 + 2 * j][p];
    unsigned int bb = s[ck * 16 + 2 * j + 1][p];
    w[j] = a | (bb << 16);
  }
  unsigned short* dst = xT + ((size_t)(b * HWc + pix0 + p)) * 64 + ck * 16;
  ((uint4*)dst)[0] = make_uint4(w[0], w[1], w[2], w[3]);
  ((uint4*)dst)[1] = make_uint4(w[4], w[5], w[6], w[7]);
}

// ---------------------------------------------------------------------------
// Kernel O: 1x1 offset conv (reads NHWC bf16) + clamp + soft-tanh -> (py,px)
// ---------------------------------------------------------------------------
__global__ __launch_bounds__(256) void k_offsets(
    const unsigned short* __restrict__ xT, const float* __restrict__ off_w,
    const float* __restrict__ off_b, float2* __restrict__ pypx) {
  __shared__ float sw[18 * 64];
  for (int i = threadIdx.x; i < 18 * 64; i += 256) sw[i] = off_w[i];
  __syncthreads();
  int t = blockIdx.x * 256 + threadIdx.x;  // == b*HWc + pix
  int b = t / HWc, pix = t % HWc;
  int h = pix / Ww, w = pix % Ww;
  const uint4* xp = (const uint4*)(xT + (size_t)t * 64);
  uint4 r[8];
#pragma unroll
  for (int j = 0; j < 8; j++) r[j] = xp[j];
  float acc[18];
#pragma unroll
  for (int o = 0; o < 18; o++) acc[o] = off_b[o];
  const unsigned int* rw = (const unsigned int*)r;
#pragma unroll
  for (int c2 = 0; c2 < 32; c2++) {
    unsigned int u = rw[c2];
    float f0 = bflo(u), f1 = bfhi(u);
#pragma unroll
    for (int o = 0; o < 18; o++)
      acc[o] += f0 * sw[o * 64 + 2 * c2] + f1 * sw[o * 64 + 2 * c2 + 1];
  }
  float fh = (float)h, fw = (float)w;
#pragma unroll
  for (int kk = 0; kk < 9; kk++) {
    float oy = fminf(fmaxf(acc[2 * kk], -fh), 160.0f - fh);
    float ox = fminf(fmaxf(acc[2 * kk + 1], -fw), 160.0f - fw);
    if (fabsf(oy) >= 8.0f) oy = 8.0f * tanhf(oy * 0.125f);
    if (fabsf(ox) >= 8.0f) ox = 8.0f * tanhf(ox * 0.125f);
    float py = fh - 1.0f + (float)(kk / 3) + oy;
    float pxv = fw - 1.0f + (float)(kk % 3) + ox;
    pypx[(b * 9 + kk) * HWc + pix] = make_float2(py, pxv);
  }
}

// ---------------------------------------------------------------------------
// Kernel 2: pre-bake weights in MFMA A-fragment order (bf16). (unchanged)
// ---------------------------------------------------------------------------
__global__ __launch_bounds__(256) void k_wpack(const float* __restrict__ wm,
                                               const float* __restrict__ wn,
                                               unsigned short* __restrict__ bf) {
  int i = blockIdx.x * 256 + threadIdx.x;
  if (i >= 9 * 2 * 12 * 64 * 8) return;
  int j2 = i & 7;
  int lane = (i >> 3) & 63;
  int ntck = i >> 9;
  int nt = ntck % 12;
  int ck = ntck / 12;
  int kk = ck >> 1;
  int chunk = ck & 1;
  int n = nt * 16 + (lane & 15);
  int c = chunk * 32 + (lane >> 4) * 8 + j2;
  float v;
  if (n < 64)
    v = wm[(n * 64 + c) * 9 + kk] + wm[((n + 64) * 64 + c) * 9 + kk];
  else
    v = wn[((n - 64) * 64 + c) * 9 + kk];
  bf[i] = f2bf(v);
}

// ---------------------------------------------------------------------------
// Kernel 3: NHWC bf16 gather (full-line dwordx4) + dbuf LDS + MFMA + epilogue
// ---------------------------------------------------------------------------
__device__ __forceinline__ void gather_batch(
    const unsigned short* __restrict__ xTb, const float2* __restrict__ pp,
    int pl, int ch8, uint4& c00, uint4& c01, uint4& c10, uint4& c11,
    float& w00, float& w01, float& w10, float& w11) {
  float2 P = pp[pl];
  float py = P.x, pxv = P.y;
  float y0f = floorf(py), x0f = floorf(pxv);
  float wy = py - y0f, wx = pxv - x0f;
  int y0 = (int)y0f, x0 = (int)x0f;
  float vy0 = (y0 >= 0 && y0 < Hh) ? 1.f : 0.f;
  float vy1 = (y0 >= -1 && y0 < Hh - 1) ? 1.f : 0.f;
  float vx0 = (x0 >= 0 && x0 < Ww) ? 1.f : 0.f;
  float vx1 = (x0 >= -1 && x0 < Ww - 1) ? 1.f : 0.f;
  int r0 = min(max(y0, 0), Hh - 1) * Ww;
  int r1 = min(max(y0 + 1, 0), Hh - 1) * Ww;
  int c0 = min(max(x0, 0), Ww - 1);
  int c1 = min(max(x0 + 1, 0), Ww - 1);
  w00 = (1.f - wy) * (1.f - wx) * vy0 * vx0;
  w01 = (1.f - wy) * wx * vy0 * vx1;
  w10 = wy * (1.f - wx) * vy1 * vx0;
  w11 = wy * wx * vy1 * vx1;
  const unsigned short* g = xTb + ch8 * 8;
  c00 = *(const uint4*)(g + (size_t)(r0 + c0) * 64);
  c01 = *(const uint4*)(g + (size_t)(r0 + c1) * 64);
  c10 = *(const uint4*)(g + (size_t)(r1 + c0) * 64);
  c11 = *(const uint4*)(g + (size_t)(r1 + c1) * 64);
}

__device__ __forceinline__ void combine_write(unsigned short* Arow,
                                              const uint4& c00, const uint4& c01,
                                              const uint4& c10, const uint4& c11,
                                              float w00, float w01, float w10,
                                              float w11) {
  const unsigned int* a = (const unsigned int*)&c00;
  const unsigned int* b = (const unsigned int*)&c01;
  const unsigned int* c = (const unsigned int*)&c10;
  const unsigned int* d = (const unsigned int*)&c11;
  unsigned int o[4];
#pragma unroll
  for (int j = 0; j < 4; j++) {
    float lo = bflo(a[j]) * w00 + bflo(b[j]) * w01 + bflo(c[j]) * w10 +
               bflo(d[j]) * w11;
    float hi = bfhi(a[j]) * w00 + bfhi(b[j]) * w01 + bfhi(c[j]) * w10 +
               bfhi(d[j]) * w11;
    o[j] = (unsigned int)f2bf(lo) | ((unsigned int)f2bf(hi) << 16);
  }
  *(uint4*)Arow = make_uint4(o[0], o[1], o[2], o[3]);
}

__global__ __launch_bounds__(256) void k_main(
    const unsigned short* __restrict__ xT, const float* __restrict__ w0,
    const float2* __restrict__ pypx, const unsigned short* __restrict__ bfrag,
    float* __restrict__ out) {
  __shared__ unsigned short A[2][64 * 72];  // [buf][px][c], rows padded to 72
  const int tid = threadIdx.x;
  const int wg = blockIdx.x;  // 1600
  const int b = wg / 400;
  const int pix0 = (wg % 400) * 64;
  const int wv = tid >> 6;
  const int l = tid & 63;
  const int lm = l & 15;
  const int quad = l >> 4;
  const int ch8 = l & 7;   // channel octet (8 bf16 = 16B)
  const int pr = l >> 3;   // pixel-in-batch 0..7

  const unsigned short* xTb = xT + (size_t)b * HWc * 64;
  const float2* ppb = pypx + (size_t)(b * 9) * HWc + pix0;

  f32x4 acc[3][4];
  const f32x4 zero = {0.f, 0.f, 0.f, 0.f};
#pragma unroll
  for (int j = 0; j < 3; j++)
#pragma unroll
    for (int pt = 0; pt < 4; pt++) acc[j][pt] = zero;

  // prologue: gather kk=0 into buf 0
#pragma unroll
  for (int i = 0; i < 2; i++) {
    int pl = wv * 16 + i * 8 + pr;
    uint4 c00, c01, c10, c11;
    float w00, w01, w10, w11;
    gather_batch(xTb, ppb, pl, ch8, c00, c01, c10, c11, w00, w01, w10, w11);
    combine_write(&A[0][pl * 72 + ch8 * 8], c00, c01, c10, c11, w00, w01, w10,
                  w11);
  }
  __syncthreads();

  for (int kk = 0; kk < 9; kk++) {
    const int cur = kk & 1;
    uint4 g00[2], g01[2], g10[2], g11[2];
    float W00[2], W01[2], W10[2], W11[2];
    if (kk < 8) {
#pragma unroll
      for (int i = 0; i < 2; i++) {
        int pl = wv * 16 + i * 8 + pr;
        gather_batch(xTb, ppb + (size_t)(kk + 1) * HWc, pl, ch8, g00[i], g01[i],
                     g10[i], g11[i], W00[i], W01[i], W10[i], W11[i]);
      }
    }
    // MFMA on current buffer
#pragma unroll
    for (int chunk = 0; chunk < 2; chunk++) {
      short8 sfr[4];
#pragma unroll
      for (int pt = 0; pt < 4; pt++)
        sfr[pt] =
            *(const short8*)&A[cur][(pt * 16 + lm) * 72 + chunk * 32 + quad * 8];
      short8 wfr[3];
#pragma unroll
      for (int j = 0; j < 3; j++) {
        int nt = j * 4 + wv;
        wfr[j] = *(const short8*)&bfrag[((size_t)((kk * 2 + chunk) * 12 + nt) *
                                            64 + l) * 8];
      }
#pragma unroll
      for (int j = 0; j < 3; j++)
#pragma unroll
        for (int pt = 0; pt < 4; pt++)
          acc[j][pt] = __builtin_amdgcn_mfma_f32_16x16x32_bf16(
              wfr[j], sfr[pt], acc[j][pt], 0, 0, 0);
    }
    if (kk < 8) {
#pragma unroll
      for (int i = 0; i < 2; i++) {
        int pl = wv * 16 + i * 8 + pr;
        combine_write(&A[cur ^ 1][pl * 72 + ch8 * 8], g00[i], g01[i], g10[i],
                      g11[i], W00[i], W01[i], W10[i], W11[i]);
      }
    }
    __syncthreads();
  }

  // epilogue: out = (pm + w0) / (1 + |qn0| + |qn1|)
  float w0v[4];
#pragma unroll
  for (int r = 0; r < 4; r++) w0v[r] = w0[wv * 16 + quad * 4 + r];
  float* ob = out + (size_t)b * Cc * HWc + pix0;
#pragma unroll
  for (int pt = 0; pt < 4; pt++) {
#pragma unroll
    for (int r = 0; r < 4; r++) {
      int oc = wv * 16 + quad * 4 + r;
      float pm = acc[0][pt][r] + w0v[r];
      float qn = 1.0f + fabsf(acc[1][pt][r]) + fabsf(acc[2][pt][r]);
      ob[oc * HWc + pt * 16 + lm] = pm / qn;
    }
  }
}

extern "C" void kernel_launch(void* const* d_in, const int* in_sizes, int n_in,
                              void* d_out, int out_size, void* d_ws, size_t ws_size,
                              hipStream_t stream) {
  const float* x = (const float*)d_in[0];      // [4,64,160,160]
  const float* off_w = (const float*)d_in[1];  // [18,64]
  const float* off_b = (const float*)d_in[2];  // [18]
  const float* w_m = (const float*)d_in[3];    // [128,64,3,3]
  const float* w_n = (const float*)d_in[4];    // [128,64,3,3]
  const float* w0 = (const float*)d_in[5];     // [64]
  float* out = (float*)d_out;                  // [4,64,160,160]

  // ws layout: pypx 7,372,800 B | bfrag 221,184 B | xT 13,107,200 B (~20.7 MB)
  float2* pypx = (float2*)d_ws;
  unsigned short* bfrag = (unsigned short*)((char*)d_ws + (size_t)7372800);
  unsigned short* xT = (unsigned short*)((char*)d_ws + (size_t)7593984);

  hipLaunchKernelGGL(k_transpose, dim3(1600), dim3(256), 0, stream, x, xT);
  hipLaunchKernelGGL(k_wpack, dim3(432), dim3(256), 0, stream, w_m, w_n, bfrag);
  hipLaunchKernelGGL(k_offsets, dim3(400), dim3(256), 0, stream, xT, off_w,
                     off_b, pypx);
  hipLaunchKernelGGL(k_main, dim3(1600), dim3(256), 0, stream, xT, w0, pypx,
                     bfrag, out);
}

// Round 4
// 154.961 us; speedup vs baseline: 2.3096x; 2.3096x over previous
//
#include <hip/hip_runtime.h>

#define Hh 160
#define Ww 160
#define Cc 64
#define HWc 25600
#define Bb 4

typedef __attribute__((ext_vector_type(8))) short short8;
typedef __attribute__((ext_vector_type(4))) float f32x4;

__device__ __forceinline__ unsigned short f2bf(float f) {
  unsigned int u = __float_as_uint(f);
  unsigned int r = u + 0x7FFFu + ((u >> 16) & 1u);
  return (unsigned short)(r >> 16);
}
__device__ __forceinline__ float bflo(unsigned int u) {
  return __uint_as_float(u << 16);
}
__device__ __forceinline__ float bfhi(unsigned int u) {
  return __uint_as_float(u & 0xffff0000u);
}

// ---------------------------------------------------------------------------
// Kernel T: NCHW f32 -> NHWC bf16 transpose. Block = 64 pixels x 64 channels.
// ---------------------------------------------------------------------------
__global__ __launch_bounds__(256) void k_transpose(const float* __restrict__ x,
                                                   unsigned short* __restrict__ xT) {
  __shared__ unsigned short s[64][65];
  int wg = blockIdx.x;           // 1600 = 4b * 400
  int b = wg / 400;
  int pix0 = (wg % 400) * 64;
  int l = threadIdx.x & 63, wv = threadIdx.x >> 6;
  const float* xb = x + (size_t)b * Cc * HWc + pix0;
#pragma unroll
  for (int i = 0; i < 16; i++) {
    int c = i * 4 + wv;
    s[c][l] = f2bf(xb[(size_t)c * HWc + l]);
  }
  __syncthreads();
  int p = threadIdx.x >> 2, ck = threadIdx.x & 3;  // 64 px x 4 chunks of 16 ch
  unsigned int w[8];
#pragma unroll
  for (int j = 0; j < 8; j++) {
    unsigned int a = s[ck * 16 + 2 * j][p];
    unsigned int bb = s[ck * 16 + 2 * j + 1][p];
    w[j] = a | (bb << 16);
  }
  unsigned short* dst = xT + ((size_t)(b * HWc + pix0 + p)) * 64 + ck * 16;
  ((uint4*)dst)[0] = make_uint4(w[0], w[1], w[2], w[3]);
  ((uint4*)dst)[1] = make_uint4(w[4], w[5], w[6], w[7]);
}

// ---------------------------------------------------------------------------
// Kernel O: 1x1 offset conv (reads NHWC bf16) + clamp + soft-tanh -> (py,px)
// Runtime j-loop keeps live ranges bounded (R2 spilled: 256 VGPR, 268MB
// scratch traffic). Weight reads are wave-uniform float4 LDS broadcasts.
// ---------------------------------------------------------------------------
__global__ __launch_bounds__(256) void k_offsets(
    const unsigned short* __restrict__ xT, const float* __restrict__ off_w,
    const float* __restrict__ off_b, float2* __restrict__ pypx) {
  __shared__ float sw[18 * 64];
  for (int i = threadIdx.x; i < 18 * 64; i += 256) sw[i] = off_w[i];
  __syncthreads();
  int t = blockIdx.x * 256 + threadIdx.x;  // == b*HWc + pix
  int b = t / HWc, pix = t % HWc;
  int h = pix / Ww, w = pix % Ww;
  const uint4* xp = (const uint4*)(xT + (size_t)t * 64);
  float acc[18];
#pragma unroll
  for (int o = 0; o < 18; o++) acc[o] = off_b[o];
  for (int j = 0; j < 8; j++) {  // runtime loop: no mega-unroll, no spill
    uint4 u4 = xp[j];
    float f0 = bflo(u4.x), f1 = bfhi(u4.x);
    float f2 = bflo(u4.y), f3 = bfhi(u4.y);
    float f4 = bflo(u4.z), f5 = bfhi(u4.z);
    float f6 = bflo(u4.w), f7 = bfhi(u4.w);
    int c0 = j * 8;
#pragma unroll
    for (int o = 0; o < 18; o++) {
      float4 wa = *(const float4*)&sw[o * 64 + c0];
      float4 wb = *(const float4*)&sw[o * 64 + c0 + 4];
      acc[o] += f0 * wa.x + f1 * wa.y + f2 * wa.z + f3 * wa.w +
                f4 * wb.x + f5 * wb.y + f6 * wb.z + f7 * wb.w;
    }
  }
  float fh = (float)h, fw = (float)w;
#pragma unroll
  for (int kk = 0; kk < 9; kk++) {
    float oy = fminf(fmaxf(acc[2 * kk], -fh), 160.0f - fh);
    float ox = fminf(fmaxf(acc[2 * kk + 1], -fw), 160.0f - fw);
    if (fabsf(oy) >= 8.0f) oy = 8.0f * tanhf(oy * 0.125f);
    if (fabsf(ox) >= 8.0f) ox = 8.0f * tanhf(ox * 0.125f);
    float py = fh - 1.0f + (float)(kk / 3) + oy;
    float pxv = fw - 1.0f + (float)(kk % 3) + ox;
    pypx[(b * 9 + kk) * HWc + pix] = make_float2(py, pxv);
  }
}

// ---------------------------------------------------------------------------
// Kernel 2: pre-bake weights in MFMA A-fragment order (bf16). (unchanged)
// ---------------------------------------------------------------------------
__global__ __launch_bounds__(256) void k_wpack(const float* __restrict__ wm,
                                               const float* __restrict__ wn,
                                               unsigned short* __restrict__ bf) {
  int i = blockIdx.x * 256 + threadIdx.x;
  if (i >= 9 * 2 * 12 * 64 * 8) return;
  int j2 = i & 7;
  int lane = (i >> 3) & 63;
  int ntck = i >> 9;
  int nt = ntck % 12;
  int ck = ntck / 12;
  int kk = ck >> 1;
  int chunk = ck & 1;
  int n = nt * 16 + (lane & 15);
  int c = chunk * 32 + (lane >> 4) * 8 + j2;
  float v;
  if (n < 64)
    v = wm[(n * 64 + c) * 9 + kk] + wm[((n + 64) * 64 + c) * 9 + kk];
  else
    v = wn[((n - 64) * 64 + c) * 9 + kk];
  bf[i] = f2bf(v);
}

// ---------------------------------------------------------------------------
// Kernel 3: NHWC bf16 gather (full-line dwordx4) + dbuf LDS + MFMA + epilogue
// ---------------------------------------------------------------------------
__device__ __forceinline__ void gather_batch(
    const unsigned short* __restrict__ xTb, const float2* __restrict__ pp,
    int pl, int ch8, uint4& c00, uint4& c01, uint4& c10, uint4& c11,
    float& w00, float& w01, float& w10, float& w11) {
  float2 P = pp[pl];
  float py = P.x, pxv = P.y;
  float y0f = floorf(py), x0f = floorf(pxv);
  float wy = py - y0f, wx = pxv - x0f;
  int y0 = (int)y0f, x0 = (int)x0f;
  float vy0 = (y0 >= 0 && y0 < Hh) ? 1.f : 0.f;
  float vy1 = (y0 >= -1 && y0 < Hh - 1) ? 1.f : 0.f;
  float vx0 = (x0 >= 0 && x0 < Ww) ? 1.f : 0.f;
  float vx1 = (x0 >= -1 && x0 < Ww - 1) ? 1.f : 0.f;
  int r0 = min(max(y0, 0), Hh - 1) * Ww;
  int r1 = min(max(y0 + 1, 0), Hh - 1) * Ww;
  int c0 = min(max(x0, 0), Ww - 1);
  int c1 = min(max(x0 + 1, 0), Ww - 1);
  w00 = (1.f - wy) * (1.f - wx) * vy0 * vx0;
  w01 = (1.f - wy) * wx * vy0 * vx1;
  w10 = wy * (1.f - wx) * vy1 * vx0;
  w11 = wy * wx * vy1 * vx1;
  const unsigned short* g = xTb + ch8 * 8;
  c00 = *(const uint4*)(g + (size_t)(r0 + c0) * 64);
  c01 = *(const uint4*)(g + (size_t)(r0 + c1) * 64);
  c10 = *(const uint4*)(g + (size_t)(r1 + c0) * 64);
  c11 = *(const uint4*)(g + (size_t)(r1 + c1) * 64);
}

__device__ __forceinline__ void combine_write(unsigned short* Arow,
                                              const uint4& c00, const uint4& c01,
                                              const uint4& c10, const uint4& c11,
                                              float w00, float w01, float w10,
                                              float w11) {
  const unsigned int* a = (const unsigned int*)&c00;
  const unsigned int* b = (const unsigned int*)&c01;
  const unsigned int* c = (const unsigned int*)&c10;
  const unsigned int* d = (const unsigned int*)&c11;
  unsigned int o[4];
#pragma unroll
  for (int j = 0; j < 4; j++) {
    float lo = bflo(a[j]) * w00 + bflo(b[j]) * w01 + bflo(c[j]) * w10 +
               bflo(d[j]) * w11;
    float hi = bfhi(a[j]) * w00 + bfhi(b[j]) * w01 + bfhi(c[j]) * w10 +
               bfhi(d[j]) * w11;
    o[j] = (unsigned int)f2bf(lo) | ((unsigned int)f2bf(hi) << 16);
  }
  *(uint4*)Arow = make_uint4(o[0], o[1], o[2], o[3]);
}

__global__ __launch_bounds__(256) void k_main(
    const unsigned short* __restrict__ xT, const float* __restrict__ w0,
    const float2* __restrict__ pypx, const unsigned short* __restrict__ bfrag,
    float* __restrict__ out) {
  __shared__ unsigned short A[2][64 * 72];  // [buf][px][c], rows padded to 72
  const int tid = threadIdx.x;
  const int wg = blockIdx.x;  // 1600
  const int b = wg / 400;
  const int pix0 = (wg % 400) * 64;
  const int wv = tid >> 6;
  const int l = tid & 63;
  const int lm = l & 15;
  const int quad = l >> 4;
  const int ch8 = l & 7;   // channel octet (8 bf16 = 16B)
  const int pr = l >> 3;   // pixel-in-batch 0..7

  const unsigned short* xTb = xT + (size_t)b * HWc * 64;
  const float2* ppb = pypx + (size_t)(b * 9) * HWc + pix0;

  f32x4 acc[3][4];
  const f32x4 zero = {0.f, 0.f, 0.f, 0.f};
#pragma unroll
  for (int j = 0; j < 3; j++)
#pragma unroll
    for (int pt = 0; pt < 4; pt++) acc[j][pt] = zero;

  // prologue: gather kk=0 into buf 0
#pragma unroll
  for (int i = 0; i < 2; i++) {
    int pl = wv * 16 + i * 8 + pr;
    uint4 c00, c01, c10, c11;
    float w00, w01, w10, w11;
    gather_batch(xTb, ppb, pl, ch8, c00, c01, c10, c11, w00, w01, w10, w11);
    combine_write(&A[0][pl * 72 + ch8 * 8], c00, c01, c10, c11, w00, w01, w10,
                  w11);
  }
  __syncthreads();

  for (int kk = 0; kk < 9; kk++) {
    const int cur = kk & 1;
    uint4 g00[2], g01[2], g10[2], g11[2];
    float W00[2], W01[2], W10[2], W11[2];
    if (kk < 8) {
#pragma unroll
      for (int i = 0; i < 2; i++) {
        int pl = wv * 16 + i * 8 + pr;
        gather_batch(xTb, ppb + (size_t)(kk + 1) * HWc, pl, ch8, g00[i], g01[i],
                     g10[i], g11[i], W00[i], W01[i], W10[i], W11[i]);
      }
    }
    // MFMA on current buffer
#pragma unroll
    for (int chunk = 0; chunk < 2; chunk++) {
      short8 sfr[4];
#pragma unroll
      for (int pt = 0; pt < 4; pt++)
        sfr[pt] =
            *(const short8*)&A[cur][(pt * 16 + lm) * 72 + chunk * 32 + quad * 8];
      short8 wfr[3];
#pragma unroll
      for (int j = 0; j < 3; j++) {
        int nt = j * 4 + wv;
        wfr[j] = *(const short8*)&bfrag[((size_t)((kk * 2 + chunk) * 12 + nt) *
                                            64 + l) * 8];
      }
#pragma unroll
      for (int j = 0; j < 3; j++)
#pragma unroll
        for (int pt = 0; pt < 4; pt++)
          acc[j][pt] = __builtin_amdgcn_mfma_f32_16x16x32_bf16(
              wfr[j], sfr[pt], acc[j][pt], 0, 0, 0);
    }
    if (kk < 8) {
#pragma unroll
      for (int i = 0; i < 2; i++) {
        int pl = wv * 16 + i * 8 + pr;
        combine_write(&A[cur ^ 1][pl * 72 + ch8 * 8], g00[i], g01[i], g10[i],
                      g11[i], W00[i], W01[i], W10[i], W11[i]);
      }
    }
    __syncthreads();
  }

  // epilogue: out = (pm + w0) / (1 + |qn0| + |qn1|)
  float w0v[4];
#pragma unroll
  for (int r = 0; r < 4; r++) w0v[r] = w0[wv * 16 + quad * 4 + r];
  float* ob = out + (size_t)b * Cc * HWc + pix0;
#pragma unroll
  for (int pt = 0; pt < 4; pt++) {
#pragma unroll
    for (int r = 0; r < 4; r++) {
      int oc = wv * 16 + quad * 4 + r;
      float pm = acc[0][pt][r] + w0v[r];
      float qn = 1.0f + fabsf(acc[1][pt][r]) + fabsf(acc[2][pt][r]);
      ob[oc * HWc + pt * 16 + lm] = pm / qn;
    }
  }
}

extern "C" void kernel_launch(void* const* d_in, const int* in_sizes, int n_in,
                              void* d_out, int out_size, void* d_ws, size_t ws_size,
                              hipStream_t stream) {
  const float* x = (const float*)d_in[0];      // [4,64,160,160]
  const float* off_w = (const float*)d_in[1];  // [18,64]
  const float* off_b = (const float*)d_in[2];  // [18]
  const float* w_m = (const float*)d_in[3];    // [128,64,3,3]
  const float* w_n = (const float*)d_in[4];    // [128,64,3,3]
  const float* w0 = (const float*)d_in[5];     // [64]
  float* out = (float*)d_out;                  // [4,64,160,160]

  // ws layout: pypx 7,372,800 B | bfrag 221,184 B | xT 13,107,200 B (~20.7 MB)
  float2* pypx = (float2*)d_ws;
  unsigned short* bfrag = (unsigned short*)((char*)d_ws + (size_t)7372800);
  unsigned short* xT = (unsigned short*)((char*)d_ws + (size_t)7593984);

  hipLaunchKernelGGL(k_transpose, dim3(1600), dim3(256), 0, stream, x, xT);
  hipLaunchKernelGGL(k_wpack, dim3(432), dim3(256), 0, stream, w_m, w_n, bfrag);
  hipLaunchKernelGGL(k_offsets, dim3(400), dim3(256), 0, stream, xT, off_w,
                     off_b, pypx);
  hipLaunchKernelGGL(k_main, dim3(1600), dim3(256), 0, stream, xT, w0, pypx,
                     bfrag, out);
}

// Round 5
// 134.482 us; speedup vs baseline: 2.6613x; 1.1523x over previous
//
#include <hip/hip_runtime.h>

#define Hh 160
#define Ww 160
#define Cc 64
#define HWc 25600
#define Bb 4

typedef __attribute__((ext_vector_type(8))) short short8;
typedef __attribute__((ext_vector_type(4))) float f32x4;

__device__ __forceinline__ unsigned short f2bf(float f) {
  unsigned int u = __float_as_uint(f);
  unsigned int r = u + 0x7FFFu + ((u >> 16) & 1u);
  return (unsigned short)(r >> 16);
}
__device__ __forceinline__ float bflo(unsigned int u) {
  return __uint_as_float(u << 16);
}
__device__ __forceinline__ float bfhi(unsigned int u) {
  return __uint_as_float(u & 0xffff0000u);
}

// ---------------------------------------------------------------------------
// Kernel T: NCHW f32 -> NHWC bf16 transpose. Block = 64 pixels x 64 channels.
// ---------------------------------------------------------------------------
__global__ __launch_bounds__(256) void k_transpose(const float* __restrict__ x,
                                                   unsigned short* __restrict__ xT) {
  __shared__ unsigned short s[64][65];
  int wg = blockIdx.x;           // 1600 = 4b * 400
  int b = wg / 400;
  int pix0 = (wg % 400) * 64;
  int l = threadIdx.x & 63, wv = threadIdx.x >> 6;
  const float* xb = x + (size_t)b * Cc * HWc + pix0;
#pragma unroll
  for (int i = 0; i < 16; i++) {
    int c = i * 4 + wv;
    s[c][l] = f2bf(xb[(size_t)c * HWc + l]);
  }
  __syncthreads();
  int p = threadIdx.x >> 2, ck = threadIdx.x & 3;  // 64 px x 4 chunks of 16 ch
  unsigned int w[8];
#pragma unroll
  for (int j = 0; j < 8; j++) {
    unsigned int a = s[ck * 16 + 2 * j][p];
    unsigned int bb = s[ck * 16 + 2 * j + 1][p];
    w[j] = a | (bb << 16);
  }
  unsigned short* dst = xT + ((size_t)(b * HWc + pix0 + p)) * 64 + ck * 16;
  ((uint4*)dst)[0] = make_uint4(w[0], w[1], w[2], w[3]);
  ((uint4*)dst)[1] = make_uint4(w[4], w[5], w[6], w[7]);
}

// ---------------------------------------------------------------------------
// Kernel W: pre-bake conv weights (110592 bf16) + offset-conv weights padded
// to 32 rows (2048 bf16), both in MFMA A-fragment order.
// ---------------------------------------------------------------------------
__global__ __launch_bounds__(256) void k_wpack(const float* __restrict__ wm,
                                               const float* __restrict__ wn,
                                               const float* __restrict__ ow,
                                               unsigned short* __restrict__ bf) {
  int i = blockIdx.x * 256 + threadIdx.x;
  if (i < 9 * 2 * 12 * 64 * 8) {
    int j2 = i & 7;
    int lane = (i >> 3) & 63;
    int ntck = i >> 9;
    int nt = ntck % 12;
    int ck = ntck / 12;
    int kk = ck >> 1;
    int chunk = ck & 1;
    int n = nt * 16 + (lane & 15);
    int c = chunk * 32 + (lane >> 4) * 8 + j2;
    float v;
    if (n < 64)
      v = wm[(n * 64 + c) * 9 + kk] + wm[((n + 64) * 64 + c) * 9 + kk];
    else
      v = wn[((n - 64) * 64 + c) * 9 + kk];
    bf[i] = f2bf(v);
  } else if (i < 9 * 2 * 12 * 64 * 8 + 2 * 2 * 64 * 8) {
    int j = i - 9 * 2 * 12 * 64 * 8;
    int j2 = j & 7;
    int lane = (j >> 3) & 63;
    int rest = j >> 9;           // chunk*2 + ntile
    int ntile = rest & 1;
    int chunk = rest >> 1;
    int n = ntile * 16 + (lane & 15);
    int c = chunk * 32 + (lane >> 4) * 8 + j2;
    bf[i] = (n < 18) ? f2bf(ow[n * 64 + c]) : (unsigned short)0;
  }
}

// ---------------------------------------------------------------------------
// Kernel M: fused offset-MFMA + bilinear gather + MFMA GEMM + pade epilogue.
// Band swizzle: band = blockIdx&7 -> one 20-row image band per XCD so the
// gather working set (~3 MB incl. halo x 4 batches) stays L2-resident.
// ---------------------------------------------------------------------------
__device__ __forceinline__ void gather_batch(
    const unsigned short* __restrict__ xTb, float2 P, int ch8, uint4& c00,
    uint4& c01, uint4& c10, uint4& c11, float& w00, float& w01, float& w10,
    float& w11) {
  float py = P.x, pxv = P.y;
  float y0f = floorf(py), x0f = floorf(pxv);
  float wy = py - y0f, wx = pxv - x0f;
  int y0 = (int)y0f, x0 = (int)x0f;
  float vy0 = (y0 >= 0 && y0 < Hh) ? 1.f : 0.f;
  float vy1 = (y0 >= -1 && y0 < Hh - 1) ? 1.f : 0.f;
  float vx0 = (x0 >= 0 && x0 < Ww) ? 1.f : 0.f;
  float vx1 = (x0 >= -1 && x0 < Ww - 1) ? 1.f : 0.f;
  int r0 = min(max(y0, 0), Hh - 1) * Ww;
  int r1 = min(max(y0 + 1, 0), Hh - 1) * Ww;
  int c0 = min(max(x0, 0), Ww - 1);
  int c1 = min(max(x0 + 1, 0), Ww - 1);
  w00 = (1.f - wy) * (1.f - wx) * vy0 * vx0;
  w01 = (1.f - wy) * wx * vy0 * vx1;
  w10 = wy * (1.f - wx) * vy1 * vx0;
  w11 = wy * wx * vy1 * vx1;
  const unsigned short* g = xTb + ch8 * 8;
  c00 = *(const uint4*)(g + (size_t)(r0 + c0) * 64);
  c01 = *(const uint4*)(g + (size_t)(r0 + c1) * 64);
  c10 = *(const uint4*)(g + (size_t)(r1 + c0) * 64);
  c11 = *(const uint4*)(g + (size_t)(r1 + c1) * 64);
}

__device__ __forceinline__ void combine_write(unsigned short* Arow,
                                              const uint4& c00, const uint4& c01,
                                              const uint4& c10, const uint4& c11,
                                              float w00, float w01, float w10,
                                              float w11) {
  const unsigned int* a = (const unsigned int*)&c00;
  const unsigned int* b = (const unsigned int*)&c01;
  const unsigned int* c = (const unsigned int*)&c10;
  const unsigned int* d = (const unsigned int*)&c11;
  unsigned int o[4];
#pragma unroll
  for (int j = 0; j < 4; j++) {
    float lo = bflo(a[j]) * w00 + bflo(b[j]) * w01 + bflo(c[j]) * w10 +
               bflo(d[j]) * w11;
    float hi = bfhi(a[j]) * w00 + bfhi(b[j]) * w01 + bfhi(c[j]) * w10 +
               bfhi(d[j]) * w11;
    o[j] = (unsigned int)f2bf(lo) | ((unsigned int)f2bf(hi) << 16);
  }
  *(uint4*)Arow = make_uint4(o[0], o[1], o[2], o[3]);
}

__global__ __launch_bounds__(256) void k_main(
    const unsigned short* __restrict__ xT, const float* __restrict__ w0,
    const float* __restrict__ off_b, const unsigned short* __restrict__ bfrag,
    const unsigned short* __restrict__ obfrag, float* __restrict__ out) {
  __shared__ unsigned short A[2][64 * 72];  // [buf][px][c], rows padded to 72
  __shared__ float2 spybuf[9][64];          // per-pixel (py,px) per kk
  const int tid = threadIdx.x;
  const int wg = blockIdx.x;  // 1600
  // band swizzle: band = wg&7 (XCD id under round-robin), 20 rows per band
  const int band = wg & 7;
  const int local = wg >> 3;   // 0..199
  const int b = local / 50;
  const int pix0 = band * 3200 + (local % 50) * 64;
  const int wv = tid >> 6;
  const int l = tid & 63;
  const int lm = l & 15;
  const int quad = l >> 4;
  const int ch8 = l & 7;   // channel octet (8 bf16 = 16B)
  const int pr = l >> 3;   // pixel-in-batch 0..7

  const unsigned short* xTb = xT + (size_t)b * HWc * 64;

  f32x4 acc[3][4];
  const f32x4 zero = {0.f, 0.f, 0.f, 0.f};
#pragma unroll
  for (int j = 0; j < 3; j++)
#pragma unroll
    for (int pt = 0; pt < 4; pt++) acc[j][pt] = zero;

  // ---- phase 0: offsets via MFMA (each wave: its 16 pixels) ----
  {
    f32x4 aO0 = zero, aO1 = zero;
    const unsigned short* xrow = xTb + (size_t)(pix0 + wv * 16 + lm) * 64;
#pragma unroll
    for (int chunk = 0; chunk < 2; chunk++) {
      short8 sb = *(const short8*)(xrow + chunk * 32 + quad * 8);
      short8 wf0 = *(const short8*)&obfrag[((chunk * 2 + 0) * 64 + l) * 8];
      short8 wf1 = *(const short8*)&obfrag[((chunk * 2 + 1) * 64 + l) * 8];
      aO0 = __builtin_amdgcn_mfma_f32_16x16x32_bf16(wf0, sb, aO0, 0, 0, 0);
      aO1 = __builtin_amdgcn_mfma_f32_16x16x32_bf16(wf1, sb, aO1, 0, 0, 0);
    }
    int pix = pix0 + wv * 16 + lm;
    int h = pix / Ww, w = pix % Ww;
    float fh = (float)h, fw = (float)w;
#pragma unroll
    for (int rr = 0; rr < 2; rr++) {
      int n = quad * 4 + 2 * rr;
      int kk = n >> 1;  // quad*2 + rr
      float oy = aO0[2 * rr] + off_b[n];
      float ox = aO0[2 * rr + 1] + off_b[n + 1];
      oy = fminf(fmaxf(oy, -fh), 160.0f - fh);
      ox = fminf(fmaxf(ox, -fw), 160.0f - fw);
      if (fabsf(oy) >= 8.0f) oy = 8.0f * tanhf(oy * 0.125f);
      if (fabsf(ox) >= 8.0f) ox = 8.0f * tanhf(ox * 0.125f);
      spybuf[kk][wv * 16 + lm] =
          make_float2(fh - 1.0f + (float)(kk / 3) + oy,
                      fw - 1.0f + (float)(kk % 3) + ox);
    }
    if (quad == 0) {  // tile1 rows 16,17 -> kk=8
      float oy = aO1[0] + off_b[16];
      float ox = aO1[1] + off_b[17];
      oy = fminf(fmaxf(oy, -fh), 160.0f - fh);
      ox = fminf(fmaxf(ox, -fw), 160.0f - fw);
      if (fabsf(oy) >= 8.0f) oy = 8.0f * tanhf(oy * 0.125f);
      if (fabsf(ox) >= 8.0f) ox = 8.0f * tanhf(ox * 0.125f);
      spybuf[8][wv * 16 + lm] =
          make_float2(fh - 1.0f + 2.0f + oy, fw - 1.0f + 2.0f + ox);
    }
  }
  __syncthreads();

  // ---- prologue: gather kk=0 into buf 0 ----
#pragma unroll
  for (int i = 0; i < 2; i++) {
    int pl = wv * 16 + i * 8 + pr;
    uint4 c00, c01, c10, c11;
    float w00, w01, w10, w11;
    gather_batch(xTb, spybuf[0][pl], ch8, c00, c01, c10, c11, w00, w01, w10,
                 w11);
    combine_write(&A[0][pl * 72 + ch8 * 8], c00, c01, c10, c11, w00, w01, w10,
                  w11);
  }
  __syncthreads();

  for (int kk = 0; kk < 9; kk++) {
    const int cur = kk & 1;
    uint4 g00[2], g01[2], g10[2], g11[2];
    float W00[2], W01[2], W10[2], W11[2];
    if (kk < 8) {
#pragma unroll
      for (int i = 0; i < 2; i++) {
        int pl = wv * 16 + i * 8 + pr;
        gather_batch(xTb, spybuf[kk + 1][pl], ch8, g00[i], g01[i], g10[i],
                     g11[i], W00[i], W01[i], W10[i], W11[i]);
      }
    }
    // MFMA on current buffer
#pragma unroll
    for (int chunk = 0; chunk < 2; chunk++) {
      short8 sfr[4];
#pragma unroll
      for (int pt = 0; pt < 4; pt++)
        sfr[pt] =
            *(const short8*)&A[cur][(pt * 16 + lm) * 72 + chunk * 32 + quad * 8];
      short8 wfr[3];
#pragma unroll
      for (int j = 0; j < 3; j++) {
        int nt = j * 4 + wv;
        wfr[j] = *(const short8*)&bfrag[((size_t)((kk * 2 + chunk) * 12 + nt) *
                                            64 + l) * 8];
      }
#pragma unroll
      for (int j = 0; j < 3; j++)
#pragma unroll
        for (int pt = 0; pt < 4; pt++)
          acc[j][pt] = __builtin_amdgcn_mfma_f32_16x16x32_bf16(
              wfr[j], sfr[pt], acc[j][pt], 0, 0, 0);
    }
    if (kk < 8) {
#pragma unroll
      for (int i = 0; i < 2; i++) {
        int pl = wv * 16 + i * 8 + pr;
        combine_write(&A[cur ^ 1][pl * 72 + ch8 * 8], g00[i], g01[i], g10[i],
                      g11[i], W00[i], W01[i], W10[i], W11[i]);
      }
    }
    __syncthreads();
  }

  // ---- epilogue: out = (pm + w0) / (1 + |qn0| + |qn1|) ----
  float w0v[4];
#pragma unroll
  for (int r = 0; r < 4; r++) w0v[r] = w0[wv * 16 + quad * 4 + r];
  float* ob = out + (size_t)b * Cc * HWc + pix0;
#pragma unroll
  for (int pt = 0; pt < 4; pt++) {
#pragma unroll
    for (int r = 0; r < 4; r++) {
      int oc = wv * 16 + quad * 4 + r;
      float pm = acc[0][pt][r] + w0v[r];
      float qn = 1.0f + fabsf(acc[1][pt][r]) + fabsf(acc[2][pt][r]);
      ob[oc * HWc + pt * 16 + lm] = pm / qn;
    }
  }
}

extern "C" void kernel_launch(void* const* d_in, const int* in_sizes, int n_in,
                              void* d_out, int out_size, void* d_ws, size_t ws_size,
                              hipStream_t stream) {
  const float* x = (const float*)d_in[0];      // [4,64,160,160]
  const float* off_w = (const float*)d_in[1];  // [18,64]
  const float* off_b = (const float*)d_in[2];  // [18]
  const float* w_m = (const float*)d_in[3];    // [128,64,3,3]
  const float* w_n = (const float*)d_in[4];    // [128,64,3,3]
  const float* w0 = (const float*)d_in[5];     // [64]
  float* out = (float*)d_out;                  // [4,64,160,160]

  // ws layout: bfrag 221184 B | obfrag 4096 B | xT 13107200 B  (~13.3 MB)
  unsigned short* bfrag = (unsigned short*)d_ws;
  unsigned short* obfrag = (unsigned short*)((char*)d_ws + (size_t)221184);
  unsigned short* xT = (unsigned short*)((char*)d_ws + (size_t)225280);

  hipLaunchKernelGGL(k_transpose, dim3(1600), dim3(256), 0, stream, x, xT);
  hipLaunchKernelGGL(k_wpack, dim3(440), dim3(256), 0, stream, w_m, w_n, off_w,
                     bfrag);
  hipLaunchKernelGGL(k_main, dim3(1600), dim3(256), 0, stream, xT, w0, off_b,
                     bfrag, obfrag, out);
}

// Round 6
// 134.132 us; speedup vs baseline: 2.6683x; 1.0026x over previous
//
#include <hip/hip_runtime.h>
#include <hip/hip_bf16.h>
#include <hip/hip_fp16.h>

#define Hh 160
#define Ww 160
#define Cc 64
#define HWc 25600
#define Bb 4

typedef __attribute__((ext_vector_type(8))) short short8;
typedef __attribute__((ext_vector_type(4))) float f32x4;

__device__ __forceinline__ unsigned short f2bf(float f) {
  unsigned int u = __float_as_uint(f);
  unsigned int r = u + 0x7FFFu + ((u >> 16) & 1u);
  return (unsigned short)(r >> 16);
}
__device__ __forceinline__ float bflo(unsigned int u) {
  return __uint_as_float(u << 16);
}
__device__ __forceinline__ float bfhi(unsigned int u) {
  return __uint_as_float(u & 0xffff0000u);
}

// ---------------------------------------------------------------------------
// Kernel P: role-split prep. Blocks [0,1600): NCHW f32 -> NHWC bf16 transpose.
// Blocks [1600,2040): weight pre-bake into MFMA A-fragment order.
// ---------------------------------------------------------------------------
__global__ __launch_bounds__(256) void k_prep(
    const float* __restrict__ x, const float* __restrict__ wm,
    const float* __restrict__ wn, const float* __restrict__ ow,
    unsigned short* __restrict__ xT, unsigned short* __restrict__ bf) {
  if (blockIdx.x < 1600) {
    __shared__ unsigned short s[64][65];
    int wg = blockIdx.x;  // 1600 = 4b * 400
    int b = wg / 400;
    int pix0 = (wg % 400) * 64;
    int l = threadIdx.x & 63, wv = threadIdx.x >> 6;
    const float* xb = x + (size_t)b * Cc * HWc + pix0;
#pragma unroll
    for (int i = 0; i < 16; i++) {
      int c = i * 4 + wv;
      s[c][l] = f2bf(xb[(size_t)c * HWc + l]);
    }
    __syncthreads();
    int p = threadIdx.x >> 2, ck = threadIdx.x & 3;
    unsigned int w[8];
#pragma unroll
    for (int j = 0; j < 8; j++) {
      unsigned int a = s[ck * 16 + 2 * j][p];
      unsigned int bb = s[ck * 16 + 2 * j + 1][p];
      w[j] = a | (bb << 16);
    }
    unsigned short* dst = xT + ((size_t)(b * HWc + pix0 + p)) * 64 + ck * 16;
    ((uint4*)dst)[0] = make_uint4(w[0], w[1], w[2], w[3]);
    ((uint4*)dst)[1] = make_uint4(w[4], w[5], w[6], w[7]);
  } else {
    int i = (blockIdx.x - 1600) * 256 + threadIdx.x;
    if (i < 9 * 2 * 12 * 64 * 8) {
      int j2 = i & 7;
      int lane = (i >> 3) & 63;
      int ntck = i >> 9;
      int nt = ntck % 12;
      int ck = ntck / 12;
      int kk = ck >> 1;
      int chunk = ck & 1;
      int n = nt * 16 + (lane & 15);
      int c = chunk * 32 + (lane >> 4) * 8 + j2;
      float v;
      if (n < 64)
        v = wm[(n * 64 + c) * 9 + kk] + wm[((n + 64) * 64 + c) * 9 + kk];
      else
        v = wn[((n - 64) * 64 + c) * 9 + kk];
      bf[i] = f2bf(v);
    } else if (i < 9 * 2 * 12 * 64 * 8 + 2 * 2 * 64 * 8) {
      int j = i - 9 * 2 * 12 * 64 * 8;
      int j2 = j & 7;
      int lane = (j >> 3) & 63;
      int rest = j >> 9;  // chunk*2 + ntile
      int ntile = rest & 1;
      int chunk = rest >> 1;
      int n = ntile * 16 + (lane & 15);
      int c = chunk * 32 + (lane >> 4) * 8 + j2;
      bf[i] = (n < 18) ? f2bf(ow[n * 64 + c]) : (unsigned short)0;
    }
  }
}

// ---------------------------------------------------------------------------
// Kernel M: fused offset-MFMA + descriptor build + gather + MFMA + epilogue.
// gdesc[kk*64+px] = {base_byte, dxB|dyB<<16, half2(w00,w01), half2(w10,w11)}
// built once per block; gathers become 4 adds + 4 dwordx4 loads.
// ---------------------------------------------------------------------------
__device__ __forceinline__ void gather2(const char* __restrict__ gbase, uint4 D,
                                        int chB, uint4& c00, uint4& c01,
                                        uint4& c10, uint4& c11, float& w00,
                                        float& w01, float& w10, float& w11) {
  int bb = D.x + chB;
  int dxB = (int)(D.y & 0xffffu);
  int dyB = (int)(D.y >> 16);
  c00 = *(const uint4*)(gbase + bb);
  c01 = *(const uint4*)(gbase + bb + dxB);
  c10 = *(const uint4*)(gbase + bb + dyB);
  c11 = *(const uint4*)(gbase + bb + (dxB + dyB));
  float2 wA = __half22float2(*(const __half2*)&D.z);
  float2 wB = __half22float2(*(const __half2*)&D.w);
  w00 = wA.x; w01 = wA.y; w10 = wB.x; w11 = wB.y;
}

__device__ __forceinline__ void combine_write(unsigned short* Arow,
                                              const uint4& c00, const uint4& c01,
                                              const uint4& c10, const uint4& c11,
                                              float w00, float w01, float w10,
                                              float w11) {
  const unsigned int* a = (const unsigned int*)&c00;
  const unsigned int* b = (const unsigned int*)&c01;
  const unsigned int* c = (const unsigned int*)&c10;
  const unsigned int* d = (const unsigned int*)&c11;
  unsigned int o[4];
#pragma unroll
  for (int j = 0; j < 4; j++) {
    float lo = bflo(a[j]) * w00 + bflo(b[j]) * w01 + bflo(c[j]) * w10 +
               bflo(d[j]) * w11;
    float hi = bfhi(a[j]) * w00 + bfhi(b[j]) * w01 + bfhi(c[j]) * w10 +
               bfhi(d[j]) * w11;
    __hip_bfloat162 hh = __float22bfloat162_rn(make_float2(lo, hi));
    o[j] = *(unsigned int*)&hh;
  }
  *(uint4*)Arow = make_uint4(o[0], o[1], o[2], o[3]);
}

__global__ __launch_bounds__(256) void k_main(
    const unsigned short* __restrict__ xT, const float* __restrict__ w0,
    const float* __restrict__ off_b, const unsigned short* __restrict__ bfrag,
    const unsigned short* __restrict__ obfrag, float* __restrict__ out) {
  __shared__ unsigned short A[2][64 * 72];  // [buf][px][c], rows padded to 72
  __shared__ uint4 gdesc[576];              // per (kk,px) gather descriptor
  float2* spy = (float2*)&A[0][0];          // overlay, dead after desc build
  const int tid = threadIdx.x;
  const int wg = blockIdx.x;  // 1600
  const int band = wg & 7;    // XCD id under round-robin
  const int local = wg >> 3;  // 0..199
  const int b = local / 50;
  const int pix0 = band * 3200 + (local % 50) * 64;
  const int wv = tid >> 6;
  const int l = tid & 63;
  const int lm = l & 15;
  const int quad = l >> 4;
  const int ch8 = l & 7;  // channel octet (16 B)
  const int pr = l >> 3;  // pixel-in-batch 0..7
  const int chB = ch8 * 16;

  const unsigned short* xTb = xT + (size_t)b * HWc * 64;
  const char* gbase = (const char*)xTb;

  f32x4 acc[3][4];
  const f32x4 zero = {0.f, 0.f, 0.f, 0.f};
#pragma unroll
  for (int j = 0; j < 3; j++)
#pragma unroll
    for (int pt = 0; pt < 4; pt++) acc[j][pt] = zero;

  // ---- phase 0: offsets via MFMA -> spy (overlay) ----
  {
    f32x4 aO0 = zero, aO1 = zero;
    const unsigned short* xrow = xTb + (size_t)(pix0 + wv * 16 + lm) * 64;
#pragma unroll
    for (int chunk = 0; chunk < 2; chunk++) {
      short8 sb = *(const short8*)(xrow + chunk * 32 + quad * 8);
      short8 wf0 = *(const short8*)&obfrag[((chunk * 2 + 0) * 64 + l) * 8];
      short8 wf1 = *(const short8*)&obfrag[((chunk * 2 + 1) * 64 + l) * 8];
      aO0 = __builtin_amdgcn_mfma_f32_16x16x32_bf16(wf0, sb, aO0, 0, 0, 0);
      aO1 = __builtin_amdgcn_mfma_f32_16x16x32_bf16(wf1, sb, aO1, 0, 0, 0);
    }
    int pix = pix0 + wv * 16 + lm;
    int h = pix / Ww, w = pix % Ww;
    float fh = (float)h, fw = (float)w;
#pragma unroll
    for (int rr = 0; rr < 2; rr++) {
      int n = quad * 4 + 2 * rr;
      int kk = n >> 1;
      float oy = aO0[2 * rr] + off_b[n];
      float ox = aO0[2 * rr + 1] + off_b[n + 1];
      oy = fminf(fmaxf(oy, -fh), 160.0f - fh);
      ox = fminf(fmaxf(ox, -fw), 160.0f - fw);
      if (fabsf(oy) >= 8.0f) oy = 8.0f * tanhf(oy * 0.125f);
      if (fabsf(ox) >= 8.0f) ox = 8.0f * tanhf(ox * 0.125f);
      spy[kk * 64 + wv * 16 + lm] =
          make_float2(fh - 1.0f + (float)(kk / 3) + oy,
                      fw - 1.0f + (float)(kk % 3) + ox);
    }
    if (quad == 0) {  // kk=8 from tile1 rows 16,17
      float oy = aO1[0] + off_b[16];
      float ox = aO1[1] + off_b[17];
      oy = fminf(fmaxf(oy, -fh), 160.0f - fh);
      ox = fminf(fmaxf(ox, -fw), 160.0f - fw);
      if (fabsf(oy) >= 8.0f) oy = 8.0f * tanhf(oy * 0.125f);
      if (fabsf(ox) >= 8.0f) ox = 8.0f * tanhf(ox * 0.125f);
      spy[8 * 64 + wv * 16 + lm] =
          make_float2(fh + 1.0f + oy, fw + 1.0f + ox);
    }
  }
  __syncthreads();

  // ---- descriptor build: 576 entries over 256 threads ----
  for (int e = tid; e < 576; e += 256) {
    float2 P = spy[e];
    float py = P.x, pxv = P.y;
    float y0f = floorf(py), x0f = floorf(pxv);
    float wy = py - y0f, wx = pxv - x0f;
    int y0 = (int)y0f, x0 = (int)x0f;
    float vy0 = (y0 >= 0 && y0 < Hh) ? 1.f : 0.f;
    float vy1 = (y0 >= -1 && y0 < Hh - 1) ? 1.f : 0.f;
    float vx0 = (x0 >= 0 && x0 < Ww) ? 1.f : 0.f;
    float vx1 = (x0 >= -1 && x0 < Ww - 1) ? 1.f : 0.f;
    int r0 = min(max(y0, 0), Hh - 1);
    int r1 = min(max(y0 + 1, 0), Hh - 1);
    int c0 = min(max(x0, 0), Ww - 1);
    int c1 = min(max(x0 + 1, 0), Ww - 1);
    float w00 = (1.f - wy) * (1.f - wx) * vy0 * vx0;
    float w01 = (1.f - wy) * wx * vy0 * vx1;
    float w10 = wy * (1.f - wx) * vy1 * vx0;
    float w11 = wy * wx * vy1 * vx1;
    uint4 D;
    D.x = (unsigned int)((r0 * Ww + c0) * 128);
    D.y = (unsigned int)((c1 - c0) * 128) | ((unsigned int)((r1 - r0) * Ww * 128) << 16);
    __half2 hA = __floats2half2_rn(w00, w01);
    __half2 hB = __floats2half2_rn(w10, w11);
    D.z = *(unsigned int*)&hA;
    D.w = *(unsigned int*)&hB;
    gdesc[e] = D;
  }
  __syncthreads();

  // ---- prologue: gather kk=0 into buf 0 ----
#pragma unroll
  for (int i = 0; i < 2; i++) {
    int pl = wv * 16 + i * 8 + pr;
    uint4 c00, c01, c10, c11;
    float w00, w01, w10, w11;
    gather2(gbase, gdesc[pl], chB, c00, c01, c10, c11, w00, w01, w10, w11);
    combine_write(&A[0][pl * 72 + ch8 * 8], c00, c01, c10, c11, w00, w01, w10,
                  w11);
  }
  __syncthreads();

  for (int kk = 0; kk < 9; kk++) {
    const int cur = kk & 1;
    uint4 g00[2], g01[2], g10[2], g11[2];
    float W00[2], W01[2], W10[2], W11[2];
    if (kk < 8) {
#pragma unroll
      for (int i = 0; i < 2; i++) {
        int pl = wv * 16 + i * 8 + pr;
        gather2(gbase, gdesc[(kk + 1) * 64 + pl], chB, g00[i], g01[i], g10[i],
                g11[i], W00[i], W01[i], W10[i], W11[i]);
      }
    }
    // MFMA on current buffer
#pragma unroll
    for (int chunk = 0; chunk < 2; chunk++) {
      short8 sfr[4];
#pragma unroll
      for (int pt = 0; pt < 4; pt++)
        sfr[pt] =
            *(const short8*)&A[cur][(pt * 16 + lm) * 72 + chunk * 32 + quad * 8];
      short8 wfr[3];
#pragma unroll
      for (int j = 0; j < 3; j++) {
        int nt = j * 4 + wv;
        wfr[j] = *(const short8*)&bfrag[((size_t)((kk * 2 + chunk) * 12 + nt) *
                                            64 + l) * 8];
      }
#pragma unroll
      for (int j = 0; j < 3; j++)
#pragma unroll
        for (int pt = 0; pt < 4; pt++)
          acc[j][pt] = __builtin_amdgcn_mfma_f32_16x16x32_bf16(
              wfr[j], sfr[pt], acc[j][pt], 0, 0, 0);
    }
    if (kk < 8) {
#pragma unroll
      for (int i = 0; i < 2; i++) {
        int pl = wv * 16 + i * 8 + pr;
        combine_write(&A[cur ^ 1][pl * 72 + ch8 * 8], g00[i], g01[i], g10[i],
                      g11[i], W00[i], W01[i], W10[i], W11[i]);
      }
    }
    __syncthreads();
  }

  // ---- epilogue: out = (pm + w0) / (1 + |qn0| + |qn1|) ----
  float w0v[4];
#pragma unroll
  for (int r = 0; r < 4; r++) w0v[r] = w0[wv * 16 + quad * 4 + r];
  float* ob = out + (size_t)b * Cc * HWc + pix0;
#pragma unroll
  for (int pt = 0; pt < 4; pt++) {
#pragma unroll
    for (int r = 0; r < 4; r++) {
      int oc = wv * 16 + quad * 4 + r;
      float pm = acc[0][pt][r] + w0v[r];
      float qn = 1.0f + fabsf(acc[1][pt][r]) + fabsf(acc[2][pt][r]);
      ob[oc * HWc + pt * 16 + lm] = pm / qn;
    }
  }
}

extern "C" void kernel_launch(void* const* d_in, const int* in_sizes, int n_in,
                              void* d_out, int out_size, void* d_ws, size_t ws_size,
                              hipStream_t stream) {
  const float* x = (const float*)d_in[0];      // [4,64,160,160]
  const float* off_w = (const float*)d_in[1];  // [18,64]
  const float* off_b = (const float*)d_in[2];  // [18]
  const float* w_m = (const float*)d_in[3];    // [128,64,3,3]
  const float* w_n = (const float*)d_in[4];    // [128,64,3,3]
  const float* w0 = (const float*)d_in[5];     // [64]
  float* out = (float*)d_out;                  // [4,64,160,160]

  // ws layout: bfrag 221184 B | obfrag 4096 B | xT 13107200 B  (~13.3 MB)
  unsigned short* bfrag = (unsigned short*)d_ws;
  unsigned short* obfrag = (unsigned short*)((char*)d_ws + (size_t)221184);
  unsigned short* xT = (unsigned short*)((char*)d_ws + (size_t)225280);

  hipLaunchKernelGGL(k_prep, dim3(2040), dim3(256), 0, stream, x, w_m, w_n,
                     off_w, xT, bfrag);
  hipLaunchKernelGGL(k_main, dim3(1600), dim3(256), 0, stream, xT, w0, off_b,
                     bfrag, obfrag, out);
}

// Round 7
// 133.625 us; speedup vs baseline: 2.6784x; 1.0038x over previous
//
#include <hip/hip_runtime.h>
#include <hip/hip_bf16.h>
#include <hip/hip_fp16.h>

#define Hh 160
#define Ww 160
#define Cc 64
#define HWc 25600
#define Bb 4
#define AST 76  // A-tile row stride in shorts (152B): 2-way banks on b128 reads

typedef __attribute__((ext_vector_type(8))) short short8;
typedef __attribute__((ext_vector_type(4))) float f32x4;

__device__ __forceinline__ unsigned short f2bf(float f) {
  unsigned int u = __float_as_uint(f);
  unsigned int r = u + 0x7FFFu + ((u >> 16) & 1u);
  return (unsigned short)(r >> 16);
}
__device__ __forceinline__ float bflo(unsigned int u) {
  return __uint_as_float(u << 16);
}
__device__ __forceinline__ float bfhi(unsigned int u) {
  return __uint_as_float(u & 0xffff0000u);
}

// ---------------------------------------------------------------------------
// Kernel P: role-split prep.
// Blocks [0,400): NCHW f32 -> NHWC bf16 transpose, 256-px tiles, float4 loads.
// Blocks [400,840): weight pre-bake into MFMA A-fragment order.
// ---------------------------------------------------------------------------
__global__ __launch_bounds__(256) void k_prep(
    const float* __restrict__ x, const float* __restrict__ wm,
    const float* __restrict__ wn, const float* __restrict__ ow,
    unsigned short* __restrict__ xT, unsigned short* __restrict__ bf) {
  if (blockIdx.x < 400) {
    __shared__ unsigned short s[64][260];
    int wg = blockIdx.x;  // 400 = 4b * 100
    int b = wg / 100;
    int pix0 = (wg % 100) * 256;
    int l = threadIdx.x & 63, wv = threadIdx.x >> 6;
    const float* xb = x + (size_t)b * Cc * HWc + pix0;
#pragma unroll
    for (int i = 0; i < 16; i++) {
      int c = i * 4 + wv;
      float4 v = *(const float4*)&xb[(size_t)c * HWc + l * 4];
      unsigned int d0 = (unsigned int)f2bf(v.x) | ((unsigned int)f2bf(v.y) << 16);
      unsigned int d1 = (unsigned int)f2bf(v.z) | ((unsigned int)f2bf(v.w) << 16);
      *(uint2*)&s[c][l * 4] = make_uint2(d0, d1);
    }
    __syncthreads();
    int p = threadIdx.x;  // pixel 0..255
    unsigned int w[32];
#pragma unroll
    for (int j = 0; j < 32; j++) {
      unsigned int a = s[2 * j][p];
      unsigned int bb = s[2 * j + 1][p];
      w[j] = a | (bb << 16);
    }
    unsigned short* dst = xT + ((size_t)(b * HWc + pix0 + p)) * 64;
#pragma unroll
    for (int j = 0; j < 8; j++)
      ((uint4*)dst)[j] = make_uint4(w[4 * j], w[4 * j + 1], w[4 * j + 2], w[4 * j + 3]);
  } else {
    int i = (blockIdx.x - 400) * 256 + threadIdx.x;
    if (i < 9 * 2 * 12 * 64 * 8) {
      int j2 = i & 7;
      int lane = (i >> 3) & 63;
      int ntck = i >> 9;
      int nt = ntck % 12;
      int ck = ntck / 12;
      int kk = ck >> 1;
      int chunk = ck & 1;
      int n = nt * 16 + (lane & 15);
      int c = chunk * 32 + (lane >> 4) * 8 + j2;
      float v;
      if (n < 64)
        v = wm[(n * 64 + c) * 9 + kk] + wm[((n + 64) * 64 + c) * 9 + kk];
      else
        v = wn[((n - 64) * 64 + c) * 9 + kk];
      bf[i] = f2bf(v);
    } else if (i < 9 * 2 * 12 * 64 * 8 + 2 * 2 * 64 * 8) {
      int j = i - 9 * 2 * 12 * 64 * 8;
      int j2 = j & 7;
      int lane = (j >> 3) & 63;
      int rest = j >> 9;  // chunk*2 + ntile
      int ntile = rest & 1;
      int chunk = rest >> 1;
      int n = ntile * 16 + (lane & 15);
      int c = chunk * 32 + (lane >> 4) * 8 + j2;
      bf[i] = (n < 18) ? f2bf(ow[n * 64 + c]) : (unsigned short)0;
    }
  }
}

// ---------------------------------------------------------------------------
// Kernel M: fused offset-MFMA + descriptor build + gather + MFMA + epilogue.
// Combine happens BEFORE the MFMA phase (writes buf^1 — safe: its readers
// finished before the previous barrier) so corner regs die early; with
// __launch_bounds__(256,4) that gives 4 blocks/CU for latency hiding via TLP.
// ---------------------------------------------------------------------------
__device__ __forceinline__ void gather2(const char* __restrict__ gbase, uint4 D,
                                        int chB, uint4& c00, uint4& c01,
                                        uint4& c10, uint4& c11, float& w00,
                                        float& w01, float& w10, float& w11) {
  int bb = D.x + chB;
  int dxB = (int)(D.y & 0xffffu);
  int dyB = (int)(D.y >> 16);
  c00 = *(const uint4*)(gbase + bb);
  c01 = *(const uint4*)(gbase + bb + dxB);
  c10 = *(const uint4*)(gbase + bb + dyB);
  c11 = *(const uint4*)(gbase + bb + (dxB + dyB));
  float2 wA = __half22float2(*(const __half2*)&D.z);
  float2 wB = __half22float2(*(const __half2*)&D.w);
  w00 = wA.x; w01 = wA.y; w10 = wB.x; w11 = wB.y;
}

__device__ __forceinline__ void combine_write(unsigned short* Arow,
                                              const uint4& c00, const uint4& c01,
                                              const uint4& c10, const uint4& c11,
                                              float w00, float w01, float w10,
                                              float w11) {
  const unsigned int* a = (const unsigned int*)&c00;
  const unsigned int* b = (const unsigned int*)&c01;
  const unsigned int* c = (const unsigned int*)&c10;
  const unsigned int* d = (const unsigned int*)&c11;
  unsigned int o[4];
#pragma unroll
  for (int j = 0; j < 4; j++) {
    float lo = bflo(a[j]) * w00 + bflo(b[j]) * w01 + bflo(c[j]) * w10 +
               bflo(d[j]) * w11;
    float hi = bfhi(a[j]) * w00 + bfhi(b[j]) * w01 + bfhi(c[j]) * w10 +
               bfhi(d[j]) * w11;
    __hip_bfloat162 hh = __float22bfloat162_rn(make_float2(lo, hi));
    o[j] = *(unsigned int*)&hh;
  }
  *(uint4*)Arow = make_uint4(o[0], o[1], o[2], o[3]);
}

__global__ __launch_bounds__(256, 4) void k_main(
    const unsigned short* __restrict__ xT, const float* __restrict__ w0,
    const float* __restrict__ off_b, const unsigned short* __restrict__ bfrag,
    const unsigned short* __restrict__ obfrag, float* __restrict__ out) {
  __shared__ unsigned short A[2][64 * AST];  // [buf][px][c]
  __shared__ uint4 gdesc[576];               // per (kk,px) gather descriptor
  float2* spy = (float2*)&A[0][0];           // overlay, dead after desc build
  const int tid = threadIdx.x;
  const int wg = blockIdx.x;  // 1600
  const int band = wg & 7;    // XCD id under round-robin
  const int local = wg >> 3;  // 0..199
  const int b = local / 50;
  const int pix0 = band * 3200 + (local % 50) * 64;
  const int wv = tid >> 6;
  const int l = tid & 63;
  const int lm = l & 15;
  const int quad = l >> 4;
  const int ch8 = l & 7;  // channel octet (16 B)
  const int pr = l >> 3;  // pixel-in-batch 0..7
  const int chB = ch8 * 16;

  const unsigned short* xTb = xT + (size_t)b * HWc * 64;
  const char* gbase = (const char*)xTb;

  f32x4 acc[3][4];
  const f32x4 zero = {0.f, 0.f, 0.f, 0.f};
#pragma unroll
  for (int j = 0; j < 3; j++)
#pragma unroll
    for (int pt = 0; pt < 4; pt++) acc[j][pt] = zero;

  // ---- phase 0: offsets via MFMA -> spy (overlay) ----
  {
    f32x4 aO0 = zero, aO1 = zero;
    const unsigned short* xrow = xTb + (size_t)(pix0 + wv * 16 + lm) * 64;
#pragma unroll
    for (int chunk = 0; chunk < 2; chunk++) {
      short8 sb = *(const short8*)(xrow + chunk * 32 + quad * 8);
      short8 wf0 = *(const short8*)&obfrag[((chunk * 2 + 0) * 64 + l) * 8];
      short8 wf1 = *(const short8*)&obfrag[((chunk * 2 + 1) * 64 + l) * 8];
      aO0 = __builtin_amdgcn_mfma_f32_16x16x32_bf16(wf0, sb, aO0, 0, 0, 0);
      aO1 = __builtin_amdgcn_mfma_f32_16x16x32_bf16(wf1, sb, aO1, 0, 0, 0);
    }
    int pix = pix0 + wv * 16 + lm;
    int h = pix / Ww, w = pix % Ww;
    float fh = (float)h, fw = (float)w;
#pragma unroll
    for (int rr = 0; rr < 2; rr++) {
      int n = quad * 4 + 2 * rr;
      int kk = n >> 1;
      float oy = aO0[2 * rr] + off_b[n];
      float ox = aO0[2 * rr + 1] + off_b[n + 1];
      oy = fminf(fmaxf(oy, -fh), 160.0f - fh);
      ox = fminf(fmaxf(ox, -fw), 160.0f - fw);
      if (fabsf(oy) >= 8.0f) oy = 8.0f * tanhf(oy * 0.125f);
      if (fabsf(ox) >= 8.0f) ox = 8.0f * tanhf(ox * 0.125f);
      spy[kk * 64 + wv * 16 + lm] =
          make_float2(fh - 1.0f + (float)(kk / 3) + oy,
                      fw - 1.0f + (float)(kk % 3) + ox);
    }
    if (quad == 0) {  // kk=8 from tile1 rows 16,17
      float oy = aO1[0] + off_b[16];
      float ox = aO1[1] + off_b[17];
      oy = fminf(fmaxf(oy, -fh), 160.0f - fh);
      ox = fminf(fmaxf(ox, -fw), 160.0f - fw);
      if (fabsf(oy) >= 8.0f) oy = 8.0f * tanhf(oy * 0.125f);
      if (fabsf(ox) >= 8.0f) ox = 8.0f * tanhf(ox * 0.125f);
      spy[8 * 64 + wv * 16 + lm] =
          make_float2(fh + 1.0f + oy, fw + 1.0f + ox);
    }
  }
  __syncthreads();

  // ---- descriptor build: 576 entries over 256 threads ----
  for (int e = tid; e < 576; e += 256) {
    float2 P = spy[e];
    float py = P.x, pxv = P.y;
    float y0f = floorf(py), x0f = floorf(pxv);
    float wy = py - y0f, wx = pxv - x0f;
    int y0 = (int)y0f, x0 = (int)x0f;
    float vy0 = (y0 >= 0 && y0 < Hh) ? 1.f : 0.f;
    float vy1 = (y0 >= -1 && y0 < Hh - 1) ? 1.f : 0.f;
    float vx0 = (x0 >= 0 && x0 < Ww) ? 1.f : 0.f;
    float vx1 = (x0 >= -1 && x0 < Ww - 1) ? 1.f : 0.f;
    int r0 = min(max(y0, 0), Hh - 1);
    int r1 = min(max(y0 + 1, 0), Hh - 1);
    int c0 = min(max(x0, 0), Ww - 1);
    int c1 = min(max(x0 + 1, 0), Ww - 1);
    float w00 = (1.f - wy) * (1.f - wx) * vy0 * vx0;
    float w01 = (1.f - wy) * wx * vy0 * vx1;
    float w10 = wy * (1.f - wx) * vy1 * vx0;
    float w11 = wy * wx * vy1 * vx1;
    uint4 D;
    D.x = (unsigned int)((r0 * Ww + c0) * 128);
    D.y = (unsigned int)((c1 - c0) * 128) |
          ((unsigned int)((r1 - r0) * Ww * 128) << 16);
    __half2 hA = __floats2half2_rn(w00, w01);
    __half2 hB = __floats2half2_rn(w10, w11);
    D.z = *(unsigned int*)&hA;
    D.w = *(unsigned int*)&hB;
    gdesc[e] = D;
  }
  __syncthreads();

  // ---- prologue: gather kk=0 into buf 0 ----
#pragma unroll
  for (int i = 0; i < 2; i++) {
    int pl = wv * 16 + i * 8 + pr;
    uint4 c00, c01, c10, c11;
    float w00, w01, w10, w11;
    gather2(gbase, gdesc[pl], chB, c00, c01, c10, c11, w00, w01, w10, w11);
    combine_write(&A[0][pl * AST + ch8 * 8], c00, c01, c10, c11, w00, w01, w10,
                  w11);
  }
  __syncthreads();

  for (int kk = 0; kk < 9; kk++) {
    const int cur = kk & 1;
    // gather + combine for kk+1 FIRST (into buf cur^1; its previous readers
    // finished before the last barrier). Corner regs die before MFMA phase.
    if (kk < 8) {
      uint4 g00[2], g01[2], g10[2], g11[2];
      float W00[2], W01[2], W10[2], W11[2];
#pragma unroll
      for (int i = 0; i < 2; i++) {
        int pl = wv * 16 + i * 8 + pr;
        gather2(gbase, gdesc[(kk + 1) * 64 + pl], chB, g00[i], g01[i], g10[i],
                g11[i], W00[i], W01[i], W10[i], W11[i]);
      }
#pragma unroll
      for (int i = 0; i < 2; i++) {
        int pl = wv * 16 + i * 8 + pr;
        combine_write(&A[cur ^ 1][pl * AST + ch8 * 8], g00[i], g01[i], g10[i],
                      g11[i], W00[i], W01[i], W10[i], W11[i]);
      }
    }
    // MFMA on current buffer
#pragma unroll
    for (int chunk = 0; chunk < 2; chunk++) {
      short8 sfr[4];
#pragma unroll
      for (int pt = 0; pt < 4; pt++)
        sfr[pt] = *(const short8*)&A[cur][(pt * 16 + lm) * AST + chunk * 32 +
                                          quad * 8];
      short8 wfr[3];
#pragma unroll
      for (int j = 0; j < 3; j++) {
        int nt = j * 4 + wv;
        wfr[j] = *(const short8*)&bfrag[((size_t)((kk * 2 + chunk) * 12 + nt) *
                                            64 + l) * 8];
      }
#pragma unroll
      for (int j = 0; j < 3; j++)
#pragma unroll
        for (int pt = 0; pt < 4; pt++)
          acc[j][pt] = __builtin_amdgcn_mfma_f32_16x16x32_bf16(
              wfr[j], sfr[pt], acc[j][pt], 0, 0, 0);
    }
    __syncthreads();
  }

  // ---- epilogue: out = (pm + w0) / (1 + |qn0| + |qn1|) ----
  float w0v[4];
#pragma unroll
  for (int r = 0; r < 4; r++) w0v[r] = w0[wv * 16 + quad * 4 + r];
  float* ob = out + (size_t)b * Cc * HWc + pix0;
#pragma unroll
  for (int pt = 0; pt < 4; pt++) {
#pragma unroll
    for (int r = 0; r < 4; r++) {
      int oc = wv * 16 + quad * 4 + r;
      float pm = acc[0][pt][r] + w0v[r];
      float qn = 1.0f + fabsf(acc[1][pt][r]) + fabsf(acc[2][pt][r]);
      ob[oc * HWc + pt * 16 + lm] = pm / qn;
    }
  }
}

extern "C" void kernel_launch(void* const* d_in, const int* in_sizes, int n_in,
                              void* d_out, int out_size, void* d_ws, size_t ws_size,
                              hipStream_t stream) {
  const float* x = (const float*)d_in[0];      // [4,64,160,160]
  const float* off_w = (const float*)d_in[1];  // [18,64]
  const float* off_b = (const float*)d_in[2];  // [18]
  const float* w_m = (const float*)d_in[3];    // [128,64,3,3]
  const float* w_n = (const float*)d_in[4];    // [128,64,3,3]
  const float* w0 = (const float*)d_in[5];     // [64]
  float* out = (float*)d_out;                  // [4,64,160,160]

  // ws layout: bfrag 221184 B | obfrag 4096 B | xT 13107200 B  (~13.3 MB)
  unsigned short* bfrag = (unsigned short*)d_ws;
  unsigned short* obfrag = (unsigned short*)((char*)d_ws + (size_t)221184);
  unsigned short* xT = (unsigned short*)((char*)d_ws + (size_t)225280);

  hipLaunchKernelGGL(k_prep, dim3(840), dim3(256), 0, stream, x, w_m, w_n,
                     off_w, xT, bfrag);
  hipLaunchKernelGGL(k_main, dim3(1600), dim3(256), 0, stream, xT, w0, off_b,
                     bfrag, obfrag, out);
}